// Round 4
// baseline (395.271 us; speedup 1.0000x reference)
//
#include <hip/hip_runtime.h>
#include <hip/hip_bf16.h>

// GAT encoder, 2 layers, N=50000, Et=850000, IN=128, HID=OUT=256, HEADS=8, C=32.
// fp16 activations + MFMA f16 GEMM (full-width 64x256 tile, fused al epilogue);
// wave-per-node segmented softmax + unroll-4 gather aggregation.

#define HEADS 8
#define F 256

typedef _Float16 h8 __attribute__((ext_vector_type(8)));
typedef _Float16 h4 __attribute__((ext_vector_type(4)));
typedef float f4 __attribute__((ext_vector_type(4)));

#define WAVE_SYNC() do { __builtin_amdgcn_wave_barrier(); \
  asm volatile("s_waitcnt lgkmcnt(0)" ::: "memory"); \
  __builtin_amdgcn_wave_barrier(); } while (0)

// ---------------- conversions ----------------

__global__ void k_cvt(const float* __restrict__ in, _Float16* __restrict__ out, int n) {
  int i = blockIdx.x * blockDim.x + threadIdx.x;
  int idx = i * 4;
  if (idx < n) {
    float4 v = *(const float4*)&in[idx];
    h4 o = {(_Float16)v.x, (_Float16)v.y, (_Float16)v.z, (_Float16)v.w};
    *(h4*)&out[idx] = o;
  }
}

// W [K][256] f32 -> Wt [256][K] fp16
__global__ void k_cvt_wt(const float* __restrict__ W, _Float16* __restrict__ Wt, int K) {
  int k = blockIdx.x, n = threadIdx.x;
  Wt[(size_t)n * K + k] = (_Float16)W[(size_t)k * F + n];
}

// ---------------- CSR build ----------------

__global__ void k_hist(const int* __restrict__ dst, int Et, int* __restrict__ deg) {
  int i = blockIdx.x * blockDim.x + threadIdx.x;
  if (i < Et) atomicAdd(&deg[dst[i]], 1);
}

__global__ __launch_bounds__(1024) void k_scan1(const int* __restrict__ deg, int n,
                                                int* __restrict__ rowptr, int* __restrict__ bsum) {
  __shared__ int s[1024];
  int i = blockIdx.x * 1024 + threadIdx.x;
  int v = (i < n) ? deg[i] : 0;
  s[threadIdx.x] = v;
  __syncthreads();
  for (int off = 1; off < 1024; off <<= 1) {
    int add = (threadIdx.x >= off) ? s[threadIdx.x - off] : 0;
    __syncthreads();
    s[threadIdx.x] += add;
    __syncthreads();
  }
  if (i < n) rowptr[i] = s[threadIdx.x] - v;
  if (threadIdx.x == 1023) bsum[blockIdx.x] = s[1023];
}

__global__ void k_scan2(const int* __restrict__ bsum, int nb, int* __restrict__ boff) {
  int t = threadIdx.x;
  int v = (t < nb) ? bsum[t] : 0;
  int inc = v;
  for (int off = 1; off < 64; off <<= 1) {
    int y = __shfl_up(inc, off, 64);
    if (t >= off) inc += y;
  }
  boff[t] = inc - v;
}

__global__ void k_scan3(int n, int Et, int* __restrict__ rowptr, const int* __restrict__ boff) {
  int i = blockIdx.x * blockDim.x + threadIdx.x;
  if (i < n) rowptr[i] += boff[i >> 10];
  if (i == 0) rowptr[n] = Et;
}

__global__ void k_fill(const int* __restrict__ src, const int* __restrict__ dst, int Et,
                       const int* __restrict__ rowptr, int* __restrict__ fill,
                       int* __restrict__ csr_src) {
  int i = blockIdx.x * blockDim.x + threadIdx.x;
  if (i < Et) {
    int d = dst[i];
    int pos = rowptr[d] + atomicAdd(&fill[d], 1);
    csr_src[pos] = src[i];
  }
}

// ---------------- MFMA GEMM + fused attention-logit epilogue ----------------
// C[M,256] = A[M,K] @ B[K,256]; 64x256 tile per block, 4 waves.
// Wave w owns rows 0..63 x cols w*64..w*64+63 = 4x4 fragments of 16x16x32.
// Bt is B transposed [256][K] so both LDS stages read contiguous K-runs.

__global__ __launch_bounds__(256) void k_gemm(const _Float16* __restrict__ A,
                                              const _Float16* __restrict__ Bt,
                                              _Float16* __restrict__ C,
                                              const float* __restrict__ a_src,
                                              const float* __restrict__ a_dst,
                                              float* __restrict__ als,
                                              float* __restrict__ ald,
                                              int M, int K) {
  __shared__ _Float16 As[64][40];    // +8 pad: 80B stride -> 2-way (free) frag reads
  __shared__ _Float16 Bs[256][40];
  int tid = threadIdx.x;
  int lane = tid & 63, w = tid >> 6;
  int rowBase = blockIdx.x * 64;
  f4 acc[4][4] = {};

  int arow = tid >> 2, akoff = (tid & 3) * 8;
  int arow_g = min(rowBase + arow, M - 1);
  const _Float16* Ap = A + (size_t)arow_g * K + akoff;
  const _Float16* Bp = Bt + (size_t)tid * K;   // thread t stages B-col t

  int kl = (lane >> 4) * 8;
  int rl = lane & 15;

  for (int k0 = 0; k0 < K; k0 += 32) {
    h8 av = *(const h8*)(Ap + k0);
    h8 bv0 = *(const h8*)(Bp + k0);
    h8 bv1 = *(const h8*)(Bp + k0 + 8);
    h8 bv2 = *(const h8*)(Bp + k0 + 16);
    h8 bv3 = *(const h8*)(Bp + k0 + 24);
    *(h8*)&As[arow][akoff] = av;
    *(h8*)&Bs[tid][0] = bv0;
    *(h8*)&Bs[tid][8] = bv1;
    *(h8*)&Bs[tid][16] = bv2;
    *(h8*)&Bs[tid][24] = bv3;
    __syncthreads();
    h8 af[4], bf[4];
#pragma unroll
    for (int fi = 0; fi < 4; ++fi) af[fi] = *(const h8*)&As[fi * 16 + rl][kl];
#pragma unroll
    for (int fj = 0; fj < 4; ++fj) bf[fj] = *(const h8*)&Bs[w * 64 + fj * 16 + rl][kl];
#pragma unroll
    for (int fi = 0; fi < 4; ++fi)
#pragma unroll
      for (int fj = 0; fj < 4; ++fj)
        acc[fi][fj] = __builtin_amdgcn_mfma_f32_16x16x32_f16(af[fi], bf[fj], acc[fi][fj], 0, 0, 0);
    __syncthreads();
  }

  int rquad = (lane >> 4) * 4;

  // C store (fp16): col = w*64 + fj*16 + rl, row = rowBase + fi*16 + rquad + r
#pragma unroll
  for (int fi = 0; fi < 4; ++fi)
#pragma unroll
    for (int fj = 0; fj < 4; ++fj) {
      int col = w * 64 + fj * 16 + rl;
#pragma unroll
      for (int r = 0; r < 4; ++r) {
        int row = rowBase + fi * 16 + rquad + r;
        if (row < M) C[(size_t)row * F + col] = (_Float16)acc[fi][fj][r];
      }
    }

  // fused al_s/al_d: wave w covers heads w*2 (fj 0,1) and w*2+1 (fj 2,3)
  int head0 = w * 2;
  float as0 = a_src[head0 * 32 + rl],      as1 = a_src[head0 * 32 + 16 + rl];
  float ad0 = a_dst[head0 * 32 + rl],      ad1 = a_dst[head0 * 32 + 16 + rl];
  float cs0 = a_src[head0 * 32 + 32 + rl], cs1 = a_src[head0 * 32 + 48 + rl];
  float cd0 = a_dst[head0 * 32 + 32 + rl], cd1 = a_dst[head0 * 32 + 48 + rl];
#pragma unroll
  for (int fi = 0; fi < 4; ++fi)
#pragma unroll
    for (int r = 0; r < 4; ++r) {
      float v0s = acc[fi][0][r] * as0 + acc[fi][1][r] * as1;
      float v0d = acc[fi][0][r] * ad0 + acc[fi][1][r] * ad1;
      float v1s = acc[fi][2][r] * cs0 + acc[fi][3][r] * cs1;
      float v1d = acc[fi][2][r] * cd0 + acc[fi][3][r] * cd1;
#pragma unroll
      for (int off = 8; off; off >>= 1) {
        v0s += __shfl_xor(v0s, off);
        v0d += __shfl_xor(v0d, off);
        v1s += __shfl_xor(v1s, off);
        v1d += __shfl_xor(v1d, off);
      }
      int row = rowBase + fi * 16 + rquad + r;
      if (rl == 0 && row < M) {
        als[row * HEADS + head0] = v0s;
        ald[row * HEADS + head0] = v0d;
        als[row * HEADS + head0 + 1] = v1s;
        ald[row * HEADS + head0 + 1] = v1d;
      }
    }
}

// ---------------- wave-per-node softmax + aggregate (+bias, ELU) ----------------
// 256 threads = 4 waves = 4 nodes. Lane layout:
//   softmax: head hh = lane>>3, slot = lane&7 (8 heads x 8 edge-slots)
//   gather:  lane owns channels lane*4..lane*4+3 (head = lane>>3, consistent)

template <bool F16OUT>
__global__ __launch_bounds__(256) void k_agg(const int* __restrict__ rowptr,
                                             const int* __restrict__ csr_src,
                                             const float* __restrict__ al_s,
                                             const float* __restrict__ al_d,
                                             const _Float16* __restrict__ h,
                                             const float* __restrict__ bias,
                                             float* __restrict__ outf,
                                             _Float16* __restrict__ outh,
                                             int n) {
  __shared__ float eps[4][64][8];
  __shared__ int ssrc[4][64];
  int tid = threadIdx.x;
  int w = tid >> 6, lane = tid & 63;
  int node = blockIdx.x * 4 + w;
  if (node >= n) return;
  int base = rowptr[node];
  int d = rowptr[node + 1] - base;
  int hh = lane >> 3, slot = lane & 7;
  float alD = al_d[node * HEADS + hh];

  float invs;
  f4 facc = {0.f, 0.f, 0.f, 0.f};
  const _Float16* hc = h + (lane << 2);

  if (d <= 64) {
    float m = -1e30f;
    for (int j = slot; j < d; j += 8) {
      int s = csr_src[base + j];
      if (hh == 0) ssrc[w][j] = s;
      float e = al_s[s * HEADS + hh] + alD;
      e = (e > 0.f) ? e : 0.2f * e;
      eps[w][j][hh] = e;
      m = fmaxf(m, e);
    }
#pragma unroll
    for (int off = 4; off; off >>= 1) m = fmaxf(m, __shfl_xor(m, off));
    float sm = 0.f;
    for (int j = slot; j < d; j += 8) {
      float p = __expf(eps[w][j][hh] - m);
      eps[w][j][hh] = p;
      sm += p;
    }
#pragma unroll
    for (int off = 4; off; off >>= 1) sm += __shfl_xor(sm, off);
    invs = 1.f / (sm + 1e-16f);
    WAVE_SYNC();
    // gather: 4-edge unroll for latency overlap
    int j = 0;
    for (; j + 4 <= d; j += 4) {
      int s0 = __builtin_amdgcn_readfirstlane(ssrc[w][j]);
      int s1 = __builtin_amdgcn_readfirstlane(ssrc[w][j + 1]);
      int s2 = __builtin_amdgcn_readfirstlane(ssrc[w][j + 2]);
      int s3 = __builtin_amdgcn_readfirstlane(ssrc[w][j + 3]);
      float p0 = eps[w][j][hh], p1 = eps[w][j + 1][hh];
      float p2 = eps[w][j + 2][hh], p3 = eps[w][j + 3][hh];
      h4 v0 = *(const h4*)(hc + ((size_t)s0 << 8));
      h4 v1 = *(const h4*)(hc + ((size_t)s1 << 8));
      h4 v2 = *(const h4*)(hc + ((size_t)s2 << 8));
      h4 v3 = *(const h4*)(hc + ((size_t)s3 << 8));
      facc.x += p0 * (float)v0.x + p1 * (float)v1.x + p2 * (float)v2.x + p3 * (float)v3.x;
      facc.y += p0 * (float)v0.y + p1 * (float)v1.y + p2 * (float)v2.y + p3 * (float)v3.y;
      facc.z += p0 * (float)v0.z + p1 * (float)v1.z + p2 * (float)v2.z + p3 * (float)v3.z;
      facc.w += p0 * (float)v0.w + p1 * (float)v1.w + p2 * (float)v2.w + p3 * (float)v3.w;
    }
    for (; j < d; ++j) {
      int s0 = __builtin_amdgcn_readfirstlane(ssrc[w][j]);
      float p0 = eps[w][j][hh];
      h4 v0 = *(const h4*)(hc + ((size_t)s0 << 8));
      facc.x += p0 * (float)v0.x;
      facc.y += p0 * (float)v0.y;
      facc.z += p0 * (float)v0.z;
      facc.w += p0 * (float)v0.w;
    }
  } else {
    // general path (rare): 2 streaming passes + chunked stage/gather
    float m = -1e30f;
    for (int j = slot; j < d; j += 8) {
      int s = csr_src[base + j];
      float e = al_s[s * HEADS + hh] + alD;
      e = (e > 0.f) ? e : 0.2f * e;
      m = fmaxf(m, e);
    }
#pragma unroll
    for (int off = 4; off; off >>= 1) m = fmaxf(m, __shfl_xor(m, off));
    float sm = 0.f;
    for (int j = slot; j < d; j += 8) {
      int s = csr_src[base + j];
      float e = al_s[s * HEADS + hh] + alD;
      e = (e > 0.f) ? e : 0.2f * e;
      sm += __expf(e - m);
    }
#pragma unroll
    for (int off = 4; off; off >>= 1) sm += __shfl_xor(sm, off);
    invs = 1.f / (sm + 1e-16f);
    for (int c0 = 0; c0 < d; c0 += 64) {
      int cn = min(64, d - c0);
      WAVE_SYNC();
      for (int j = slot; j < cn; j += 8) {
        int s = csr_src[base + c0 + j];
        if (hh == 0) ssrc[w][j] = s;
        float e = al_s[s * HEADS + hh] + alD;
        e = (e > 0.f) ? e : 0.2f * e;
        eps[w][j][hh] = __expf(e - m);
      }
      WAVE_SYNC();
      for (int j = 0; j < cn; ++j) {
        int s0 = __builtin_amdgcn_readfirstlane(ssrc[w][j]);
        float p0 = eps[w][j][hh];
        h4 v0 = *(const h4*)(hc + ((size_t)s0 << 8));
        facc.x += p0 * (float)v0.x;
        facc.y += p0 * (float)v0.y;
        facc.z += p0 * (float)v0.z;
        facc.w += p0 * (float)v0.w;
      }
    }
  }

  int c0 = lane << 2;
  float4 bv = *(const float4*)&bias[c0];
  float o0 = facc.x * invs + bv.x;
  float o1 = facc.y * invs + bv.y;
  float o2 = facc.z * invs + bv.z;
  float o3 = facc.w * invs + bv.w;
  o0 = (o0 > 0.f) ? o0 : expm1f(o0);
  o1 = (o1 > 0.f) ? o1 : expm1f(o1);
  o2 = (o2 > 0.f) ? o2 : expm1f(o2);
  o3 = (o3 > 0.f) ? o3 : expm1f(o3);
  if (F16OUT) {
    h4 o = {(_Float16)o0, (_Float16)o1, (_Float16)o2, (_Float16)o3};
    *(h4*)&outh[((size_t)node << 8) + c0] = o;
  } else {
    *(float4*)&outf[((size_t)node << 8) + c0] = make_float4(o0, o1, o2, o3);
  }
}

// ---------------- launch ----------------

extern "C" void kernel_launch(void* const* d_in, const int* in_sizes, int n_in,
                              void* d_out, int out_size, void* d_ws, size_t ws_size,
                              hipStream_t stream) {
  const float* x   = (const float*)d_in[0];
  const int*   ei  = (const int*)d_in[1];
  const float* W1  = (const float*)d_in[2];
  const float* a1s = (const float*)d_in[3];
  const float* a1d = (const float*)d_in[4];
  const float* b1  = (const float*)d_in[5];
  const float* W2  = (const float*)d_in[6];
  const float* a2s = (const float*)d_in[7];
  const float* a2d = (const float*)d_in[8];
  const float* b2  = (const float*)d_in[9];

  int n  = in_sizes[0] / 128;   // 50000
  int Et = in_sizes[1] / 2;     // 850000
  const int* srcp = ei;
  const int* dstp = ei + Et;

  char* ws = (char*)d_ws;
  auto alloc = [&](size_t bytes) {
    char* p = ws;
    ws += (bytes + 255) & ~(size_t)255;
    return p;
  };
  _Float16* xh     = (_Float16*)alloc((size_t)n * 128 * 2);
  _Float16* hbuf   = (_Float16*)alloc((size_t)n * F * 2);
  _Float16* Wt1    = (_Float16*)alloc((size_t)128 * F * 2);
  _Float16* Wt2    = (_Float16*)alloc((size_t)F * F * 2);
  float*    als    = (float*)alloc((size_t)n * HEADS * 4);
  float*    ald    = (float*)alloc((size_t)n * HEADS * 4);
  int*      deg    = (int*)alloc((size_t)n * 4);
  int*      fill   = (int*)alloc((size_t)n * 4);
  int*      rowptr = (int*)alloc((size_t)(n + 1) * 4);
  int*      bsum   = (int*)alloc(64 * 4);
  int*      boff   = (int*)alloc(64 * 4);
  int*      csr    = (int*)alloc((size_t)Et * 4);
  _Float16* out1h  = (_Float16*)d_out;  // layer-1 fp16 staged in d_out
  float*    outF   = (float*)d_out;

  hipMemsetAsync(deg, 0, (size_t)n * 4, stream);
  hipMemsetAsync(fill, 0, (size_t)n * 4, stream);

  k_cvt<<<(n * 128 / 4 + 255) / 256, 256, 0, stream>>>(x, xh, n * 128);
  k_cvt_wt<<<128, 256, 0, stream>>>(W1, Wt1, 128);
  k_cvt_wt<<<256, 256, 0, stream>>>(W2, Wt2, 256);

  int eb = (Et + 255) / 256;
  k_hist<<<eb, 256, 0, stream>>>(dstp, Et, deg);
  int nb = (n + 1023) / 1024;
  k_scan1<<<nb, 1024, 0, stream>>>(deg, n, rowptr, bsum);
  k_scan2<<<1, 64, 0, stream>>>(bsum, nb, boff);
  k_scan3<<<(n + 255) / 256, 256, 0, stream>>>(n, Et, rowptr, boff);
  k_fill<<<eb, 256, 0, stream>>>(srcp, dstp, Et, rowptr, fill, csr);

  int gb = (n + 63) / 64;
  int ab = (n + 3) / 4;
  // layer 1
  k_gemm<<<gb, 256, 0, stream>>>(xh, Wt1, hbuf, a1s, a1d, als, ald, n, 128);
  k_agg<true><<<ab, 256, 0, stream>>>(rowptr, csr, als, ald, hbuf, b1, nullptr, out1h, n);
  // layer 2
  k_gemm<<<gb, 256, 0, stream>>>(out1h, Wt2, hbuf, a2s, a2d, als, ald, n, 256);
  k_agg<false><<<ab, 256, 0, stream>>>(rowptr, csr, als, ald, hbuf, b2, outF, nullptr, n);
}